// Round 1
// baseline (531.483 us; speedup 1.0000x reference)
//
#include <hip/hip_runtime.h>

// SparseGrid trilinear interpolation (Plenoxels-style).
// reso = 128^3, data_dim = 28, npts = 2,000,000.
// Mapping: p = pt * (0.5/R * gsz) + (0.5*(1-C/R)*gsz - 0.5) = pt*64 + 63.5
// (R=1, C=0, gsz=128 — both constants exact in f32).

#define RES 128
#define DD  28   // 9*3+1

__global__ __launch_bounds__(256) void trilerp_kernel(
    const float* __restrict__ data,
    const float* __restrict__ points,
    const int*   __restrict__ links,
    float*       __restrict__ out,
    int npts)
{
    int p = blockIdx.x * blockDim.x + threadIdx.x;
    if (p >= npts) return;

    float px = points[p * 3 + 0] * 64.0f + 63.5f;
    float py = points[p * 3 + 1] * 64.0f + 63.5f;
    float pz = points[p * 3 + 2] * 64.0f + 63.5f;

    px = fminf(fmaxf(px, 0.0f), 127.0f);
    py = fminf(fmaxf(py, 0.0f), 127.0f);
    pz = fminf(fmaxf(pz, 0.0f), 127.0f);

    int lx = min((int)px, RES - 2);
    int ly = min((int)py, RES - 2);
    int lz = min((int)pz, RES - 2);

    float wbx = px - (float)lx, wby = py - (float)ly, wbz = pz - (float)lz;
    float wax = 1.0f - wbx,     way = 1.0f - wby,     waz = 1.0f - wbz;

    int base = (lx * RES + ly) * RES + lz;

    int ls[8];
    ls[0] = links[base];
    ls[1] = links[base + 1];
    ls[2] = links[base + RES];
    ls[3] = links[base + RES + 1];
    ls[4] = links[base + RES * RES];
    ls[5] = links[base + RES * RES + 1];
    ls[6] = links[base + RES * RES + RES];
    ls[7] = links[base + RES * RES + RES + 1];

    float w[8];
    w[0] = wax * way * waz;
    w[1] = wax * way * wbz;
    w[2] = wax * wby * waz;
    w[3] = wax * wby * wbz;
    w[4] = wbx * way * waz;
    w[5] = wbx * way * wbz;
    w[6] = wbx * wby * waz;
    w[7] = wbx * wby * wbz;

    float4 acc[7];
#pragma unroll
    for (int j = 0; j < 7; ++j) acc[j] = make_float4(0.f, 0.f, 0.f, 0.f);

#pragma unroll
    for (int i = 0; i < 8; ++i) {
        int   li = ls[i] >= 0 ? ls[i] : 0;
        float wi = ls[i] >= 0 ? w[i] : 0.0f;
        // data row is 28 floats = 112 B; 112 % 16 == 0 so float4-aligned.
        const float4* row = (const float4*)(data + (long)li * DD);
#pragma unroll
        for (int j = 0; j < 7; ++j) {
            float4 v = row[j];
            acc[j].x += wi * v.x;
            acc[j].y += wi * v.y;
            acc[j].z += wi * v.z;
            acc[j].w += wi * v.w;
        }
    }

    float4* o = (float4*)(out + (long)p * DD);
#pragma unroll
    for (int j = 0; j < 7; ++j) o[j] = acc[j];
}

extern "C" void kernel_launch(void* const* d_in, const int* in_sizes, int n_in,
                              void* d_out, int out_size, void* d_ws, size_t ws_size,
                              hipStream_t stream) {
    const float* data   = (const float*)d_in[0];
    const float* points = (const float*)d_in[1];
    const int*   links  = (const int*)d_in[2];
    float*       out    = (float*)d_out;

    int npts = in_sizes[1] / 3;

    const int block = 256;
    const int grid  = (npts + block - 1) / block;
    hipLaunchKernelGGL(trilerp_kernel, dim3(grid), dim3(block), 0, stream,
                       data, points, links, out, npts);
}

// Round 2
// 528.033 us; speedup vs baseline: 1.0065x; 1.0065x over previous
//
#include <hip/hip_runtime.h>

// SparseGrid trilinear interpolation (Plenoxels-style).
// reso = 128^3, data_dim = 28, npts = 2,000,000.
// Mapping: p = pt*64 + 63.5 (R=1, C=0, gsz=128 — exact in f32).
//
// Round-2 structure: 7 threads per point, one per float4 channel-chunk.
// - 7x memory-level parallelism vs 1-thread-per-point (latency-bound fix)
// - 7 consecutive lanes read 7 consecutive float4 of the same gathered row
// - out writes are fully contiguous across the block

#define RES 128
#define DD  28     // 9*3+1 floats per row
#define PPB 64     // points per block
#define TPB (PPB * 7)  // 448 threads = 7 waves

__global__ __launch_bounds__(TPB) void trilerp_kernel(
    const float* __restrict__ data,
    const float* __restrict__ points,
    const int*   __restrict__ links,
    float*       __restrict__ out,
    int npts)
{
    const int tid = threadIdx.x;
    const int j   = tid % 7;        // float4 chunk within the 28-float row
    const int pl  = tid / 7;        // local point index
    const int p   = blockIdx.x * PPB + pl;
    if (p >= npts) return;

    float px = points[p * 3 + 0] * 64.0f + 63.5f;
    float py = points[p * 3 + 1] * 64.0f + 63.5f;
    float pz = points[p * 3 + 2] * 64.0f + 63.5f;

    px = fminf(fmaxf(px, 0.0f), 127.0f);
    py = fminf(fmaxf(py, 0.0f), 127.0f);
    pz = fminf(fmaxf(pz, 0.0f), 127.0f);

    int lx = min((int)px, RES - 2);
    int ly = min((int)py, RES - 2);
    int lz = min((int)pz, RES - 2);

    float wbx = px - (float)lx, wby = py - (float)ly, wbz = pz - (float)lz;
    float wax = 1.0f - wbx,     way = 1.0f - wby,     waz = 1.0f - wbz;

    const int base = (lx * RES + ly) * RES + lz;

    int ls[8];
    ls[0] = links[base];
    ls[1] = links[base + 1];
    ls[2] = links[base + RES];
    ls[3] = links[base + RES + 1];
    ls[4] = links[base + RES * RES];
    ls[5] = links[base + RES * RES + 1];
    ls[6] = links[base + RES * RES + RES];
    ls[7] = links[base + RES * RES + RES + 1];

    float w[8];
    w[0] = wax * way * waz;
    w[1] = wax * way * wbz;
    w[2] = wax * wby * waz;
    w[3] = wax * wby * wbz;
    w[4] = wbx * way * waz;
    w[5] = wbx * way * wbz;
    w[6] = wbx * wby * waz;
    w[7] = wbx * wby * wbz;

    // Issue all 8 gathers (one float4 each) before accumulating — 8 loads
    // in flight per thread, ~32 VGPRs.
    float4 v[8];
#pragma unroll
    for (int i = 0; i < 8; ++i) {
        const int li = ls[i] >= 0 ? ls[i] : 0;
        v[i] = ((const float4*)(data + (long)li * DD))[j];
    }

    float4 acc = make_float4(0.f, 0.f, 0.f, 0.f);
#pragma unroll
    for (int i = 0; i < 8; ++i) {
        const float wi = ls[i] >= 0 ? w[i] : 0.0f;
        acc.x += wi * v[i].x;
        acc.y += wi * v[i].y;
        acc.z += wi * v[i].z;
        acc.w += wi * v[i].w;
    }

    // out offset: p*28 + j*4 == blockIdx.x*PPB*28 + tid*4  (contiguous)
    float4* o = (float4*)(out + (long)blockIdx.x * PPB * DD + (long)tid * 4);
    *o = acc;
}

extern "C" void kernel_launch(void* const* d_in, const int* in_sizes, int n_in,
                              void* d_out, int out_size, void* d_ws, size_t ws_size,
                              hipStream_t stream) {
    const float* data   = (const float*)d_in[0];
    const float* points = (const float*)d_in[1];
    const int*   links  = (const int*)d_in[2];
    float*       out    = (float*)d_out;

    int npts = in_sizes[1] / 3;

    const int grid = (npts + PPB - 1) / PPB;
    hipLaunchKernelGGL(trilerp_kernel, dim3(grid), dim3(TPB), 0, stream,
                       data, points, links, out, npts);
}

// Round 4
// 523.837 us; speedup vs baseline: 1.0146x; 1.0080x over previous
//
#include <hip/hip_runtime.h>

// SparseGrid trilinear interpolation (Plenoxels-style).
// reso = 128^3, data_dim = 28, npts = 2,000,000.
// Mapping: p = pt*64 + 63.5 (R=1, C=0, gsz=128 — exact in f32).
//
// Round-4: round-2 structure (7 threads/point, float4 channel chunks)
// + NON-TEMPORAL out stores (via native ext_vector_type — the HIP
// float4 class type is rejected by __builtin_nontemporal_store).
// Theory: the 224 MB output write-stream was flushing the 224 MB data
// table out of the 256 MB Infinity Cache, forcing every corner gather
// (1.8 GB/dispatch) to HBM. nt stores keep the write stream from
// evicting; data should stay L3-resident within/across dispatches.

#define RES 128
#define DD  28     // 9*3+1 floats per row
#define PPB 64     // points per block
#define TPB (PPB * 7)  // 448 threads = 7 waves

typedef float vf4 __attribute__((ext_vector_type(4)));

__global__ __launch_bounds__(TPB) void trilerp_kernel(
    const float* __restrict__ data,
    const float* __restrict__ points,
    const int*   __restrict__ links,
    float*       __restrict__ out,
    int npts)
{
    const int tid = threadIdx.x;
    const int j   = tid % 7;        // float4 chunk within the 28-float row
    const int pl  = tid / 7;        // local point index
    const int p   = blockIdx.x * PPB + pl;
    if (p >= npts) return;

    float px = points[p * 3 + 0] * 64.0f + 63.5f;
    float py = points[p * 3 + 1] * 64.0f + 63.5f;
    float pz = points[p * 3 + 2] * 64.0f + 63.5f;

    px = fminf(fmaxf(px, 0.0f), 127.0f);
    py = fminf(fmaxf(py, 0.0f), 127.0f);
    pz = fminf(fmaxf(pz, 0.0f), 127.0f);

    int lx = min((int)px, RES - 2);
    int ly = min((int)py, RES - 2);
    int lz = min((int)pz, RES - 2);

    float wbx = px - (float)lx, wby = py - (float)ly, wbz = pz - (float)lz;
    float wax = 1.0f - wbx,     way = 1.0f - wby,     waz = 1.0f - wbz;

    const int base = (lx * RES + ly) * RES + lz;

    int ls[8];
    ls[0] = links[base];
    ls[1] = links[base + 1];
    ls[2] = links[base + RES];
    ls[3] = links[base + RES + 1];
    ls[4] = links[base + RES * RES];
    ls[5] = links[base + RES * RES + 1];
    ls[6] = links[base + RES * RES + RES];
    ls[7] = links[base + RES * RES + RES + 1];

    float w[8];
    w[0] = wax * way * waz;
    w[1] = wax * way * wbz;
    w[2] = wax * wby * waz;
    w[3] = wax * wby * wbz;
    w[4] = wbx * way * waz;
    w[5] = wbx * way * wbz;
    w[6] = wbx * wby * waz;
    w[7] = wbx * wby * wbz;

    // Issue all 8 gathers (one float4 each) before accumulating.
    vf4 v[8];
#pragma unroll
    for (int i = 0; i < 8; ++i) {
        const int li = ls[i] >= 0 ? ls[i] : 0;
        v[i] = *(const vf4*)(data + (long)li * DD + j * 4);
    }

    vf4 acc = (vf4)(0.0f);
#pragma unroll
    for (int i = 0; i < 8; ++i) {
        const float wi = ls[i] >= 0 ? w[i] : 0.0f;
        acc += wi * v[i];
    }

    // out offset: p*28 + j*4 == blockIdx.x*PPB*28 + tid*4  (contiguous).
    // Non-temporal: don't let this 224 MB stream evict `data` from L2/MALL.
    vf4* o = (vf4*)(out + (long)blockIdx.x * PPB * DD + (long)tid * 4);
    __builtin_nontemporal_store(acc, o);
}

extern "C" void kernel_launch(void* const* d_in, const int* in_sizes, int n_in,
                              void* d_out, int out_size, void* d_ws, size_t ws_size,
                              hipStream_t stream) {
    const float* data   = (const float*)d_in[0];
    const float* points = (const float*)d_in[1];
    const int*   links  = (const int*)d_in[2];
    float*       out    = (float*)d_out;

    int npts = in_sizes[1] / 3;

    const int grid = (npts + PPB - 1) / PPB;
    hipLaunchKernelGGL(trilerp_kernel, dim3(grid), dim3(TPB), 0, stream,
                       data, points, links, out, npts);
}

// Round 5
// 473.613 us; speedup vs baseline: 1.1222x; 1.1060x over previous
//
#include <hip/hip_runtime.h>

// SparseGrid trilinear interpolation (Plenoxels-style).
// reso = 128^3, data_dim = 28, npts = 2,000,000.
// Mapping: p = pt*64 + 63.5 (R=1, C=0, gsz=128 — exact in f32).
//
// Round-5: SLAB PARTITIONING for L3 residency.
// links == arange, so data rows are laid out exactly like the 128^3 grid.
// Split the grid into SLABS x-slabs (~59 MB contiguous data each). Grid is
// SLABS x bigger; block group s only processes points whose cell x-index
// falls in slab s. Blocks dispatch roughly in blockIdx order, so each
// slab's data stays MALL-resident while its points run -> each data row
// fetched from HBM ~once (224 MB) instead of ~8x (1.8 GB).
// Structure per point unchanged from round-2: 7 threads/point, one float4
// channel-chunk each; nt store for out.

#define RES 128
#define DD  28     // 9*3+1 floats per row
#define PPB 64     // points per block
#define TPB (PPB * 7)  // 448 threads = 7 waves
#define SLABS 4
#define SLABW (RES / SLABS)  // 32 x-planes per slab

typedef float vf4 __attribute__((ext_vector_type(4)));

__global__ __launch_bounds__(TPB) void trilerp_kernel(
    const float* __restrict__ data,
    const float* __restrict__ points,
    const int*   __restrict__ links,
    float*       __restrict__ out,
    int npts, int nb)
{
    const int slab   = blockIdx.x / nb;   // 0..SLABS-1, low blockIdx = slab 0
    const int pblock = blockIdx.x % nb;

    const int tid = threadIdx.x;
    const int j   = tid % 7;        // float4 chunk within the 28-float row
    const int pl  = tid / 7;        // local point index
    const int p   = pblock * PPB + pl;
    if (p >= npts) return;

    float px = points[p * 3 + 0] * 64.0f + 63.5f;
    float py = points[p * 3 + 1] * 64.0f + 63.5f;
    float pz = points[p * 3 + 2] * 64.0f + 63.5f;

    px = fminf(fmaxf(px, 0.0f), 127.0f);
    py = fminf(fmaxf(py, 0.0f), 127.0f);
    pz = fminf(fmaxf(pz, 0.0f), 127.0f);

    int lx = min((int)px, RES - 2);
    int ly = min((int)py, RES - 2);
    int lz = min((int)pz, RES - 2);

    // Slab membership: this point belongs to exactly one slab.
    if ((lx >> 5) != slab) return;   // SLABW == 32

    float wbx = px - (float)lx, wby = py - (float)ly, wbz = pz - (float)lz;
    float wax = 1.0f - wbx,     way = 1.0f - wby,     waz = 1.0f - wbz;

    const int base = (lx * RES + ly) * RES + lz;

    int ls[8];
    ls[0] = links[base];
    ls[1] = links[base + 1];
    ls[2] = links[base + RES];
    ls[3] = links[base + RES + 1];
    ls[4] = links[base + RES * RES];
    ls[5] = links[base + RES * RES + 1];
    ls[6] = links[base + RES * RES + RES];
    ls[7] = links[base + RES * RES + RES + 1];

    float w[8];
    w[0] = wax * way * waz;
    w[1] = wax * way * wbz;
    w[2] = wax * wby * waz;
    w[3] = wax * wby * wbz;
    w[4] = wbx * way * waz;
    w[5] = wbx * way * wbz;
    w[6] = wbx * wby * waz;
    w[7] = wbx * wby * wbz;

    // Issue all 8 gathers (one float4 each) before accumulating.
    vf4 v[8];
#pragma unroll
    for (int i = 0; i < 8; ++i) {
        const int li = ls[i] >= 0 ? ls[i] : 0;
        v[i] = *(const vf4*)(data + (long)li * DD + j * 4);
    }

    vf4 acc = (vf4)(0.0f);
#pragma unroll
    for (int i = 0; i < 8; ++i) {
        const float wi = ls[i] >= 0 ? w[i] : 0.0f;
        acc += wi * v[i];
    }

    // out offset: p*28 + j*4 (16B-aligned). nt: out is write-once.
    vf4* o = (vf4*)(out + (long)p * DD + (long)j * 4);
    __builtin_nontemporal_store(acc, o);
}

extern "C" void kernel_launch(void* const* d_in, const int* in_sizes, int n_in,
                              void* d_out, int out_size, void* d_ws, size_t ws_size,
                              hipStream_t stream) {
    const float* data   = (const float*)d_in[0];
    const float* points = (const float*)d_in[1];
    const int*   links  = (const int*)d_in[2];
    float*       out    = (float*)d_out;

    int npts = in_sizes[1] / 3;

    const int nb   = (npts + PPB - 1) / PPB;
    const int grid = nb * SLABS;
    hipLaunchKernelGGL(trilerp_kernel, dim3(grid), dim3(TPB), 0, stream,
                       data, points, links, out, npts, nb);
}